// Round 4
// baseline (555.757 us; speedup 1.0000x reference)
//
#include <hip/hip_runtime.h>

#define B_   4
#define C_   64
#define H_   128
#define W_   128
#define KS   7
#define G_   4
#define GC_  16
#define KK   49
#define PAD  3
#define TH   16
#define TW   16
#define HW_  (H_ * W_)
#define HALO_H 22
#define HALO_W 22
#define CSTRIDE 485            // dwords per halo channel (22*22+1, breaks bank pattern)
#define ZROWB 544              // bytes per z k-row: 256 px * 2B + 32B pad (16B aligned)

typedef float f32x4  __attribute__((ext_vector_type(4)));
typedef short bf16x8 __attribute__((ext_vector_type(8)));
typedef unsigned int u32x4 __attribute__((ext_vector_type(4)));
typedef unsigned int u32x2 __attribute__((ext_vector_type(2)));

__device__ __forceinline__ unsigned f2bf(float f) {   // RNE float->bf16 (low 16)
    unsigned u = __float_as_uint(f);
    unsigned r = u + 0x7FFFu + ((u >> 16) & 1u);
    return r >> 16;
}

#define BFLO(u) __uint_as_float((u) << 16)
#define BFHI(u) __uint_as_float((u) & 0xFFFF0000u)

__global__ __launch_bounds__(256, 2) void invol_mfma3(
    const float* __restrict__ x,
    const float* __restrict__ cw,
    const float* __restrict__ bng,
    const float* __restrict__ bnb,
    const float* __restrict__ bnm,
    const float* __restrict__ bnv,
    float* __restrict__ out)
{
    __shared__ float halo[GC_ * CSTRIDE];                        // 31040 B
    __shared__ __align__(16) unsigned short z_sh[KK * (ZROWB / 2)]; // 26656 B
    __shared__ float sscale[KK], sbias[KK];

    const int tid  = threadIdx.x;
    const int lane = tid & 63;
    const int wv   = tid >> 6;        // wave 0..3
    const int l15  = lane & 15;
    const int l4   = lane >> 4;

    const int w0 = blockIdx.x * TW;
    const int h0 = blockIdx.y * TH;
    const int bz = blockIdx.z;        // b*G + g
    const int b  = bz >> 2;
    const int g  = bz & 3;

    // ---- BN constants ----
    if (tid < KK) {
        const int o = g * KK + tid;
        const float s = bng[o] * rsqrtf(bnv[o] + 1e-5f);
        sscale[tid] = s;
        sbias[tid]  = bnb[o] - bnm[o] * s;
    }

    // ---- stage halo: [c][22r][22c], channel stride 485 dwords, zero-padded ----
    const float* xg = x + (size_t)(b * C_ + g * GC_) * HW_;
    for (int i = tid; i < GC_ * HALO_H * HALO_W; i += 256) {
        const int c  = i / (HALO_H * HALO_W);
        const int r  = i - c * (HALO_H * HALO_W);
        const int hh = r / HALO_W;
        const int ww = r - hh * HALO_W;
        const int gh = h0 + hh - PAD;
        const int gw = w0 + ww - PAD;
        float v = 0.0f;
        if (gh >= 0 && gh < H_ && gw >= 0 && gw < W_)
            v = xg[c * HW_ + gh * W_ + gw];
        halo[c * CSTRIDE + hh * HALO_W + ww] = v;
    }

    // ---- A fragments: A[px][c], px = (wv*4+mt)*16 + l15 ----
    bf16x8 afr[4][2];
    {
        const float* xb = x + (size_t)b * C_ * HW_;
#pragma unroll
        for (int mt = 0; mt < 4; ++mt) {
            const int hh = h0 + wv * 4 + mt;
            const float* xp = xb + hh * W_ + (w0 + l15);
#pragma unroll
            for (int ks = 0; ks < 2; ++ks) {
                const int c0 = ks * 32 + l4 * 8;
                bf16x8 a;
#pragma unroll
                for (int j = 0; j < 8; ++j)
                    a[j] = (short)f2bf(xp[(size_t)(c0 + j) * HW_]);
                afr[mt][ks] = a;
            }
        }
    }

    // ---- B fragments: B[c][k], k = nt*16 + l15 (zero-padded past 49) ----
    bf16x8 bfr[4][2];
    {
#pragma unroll
        for (int nt = 0; nt < 4; ++nt) {
            const int kout = nt * 16 + l15;
            const bool kv = (kout < KK);
            const float* wp = cw + (size_t)(g * KK + (kv ? kout : 0)) * C_;
#pragma unroll
            for (int ks = 0; ks < 2; ++ks) {
                const int c0 = ks * 32 + l4 * 8;
                bf16x8 bb;
#pragma unroll
                for (int j = 0; j < 8; ++j)
                    bb[j] = kv ? (short)f2bf(wp[c0 + j]) : (short)0;
                bfr[nt][ks] = bb;
            }
        }
    }

    __syncthreads();   // halo + BN consts staged

    // ---- MFMA: z[px][k] ----
    f32x4 acc1[4][4];
#pragma unroll
    for (int mt = 0; mt < 4; ++mt)
#pragma unroll
        for (int nt = 0; nt < 4; ++nt) {
            f32x4 a = {0.f, 0.f, 0.f, 0.f};
            a = __builtin_amdgcn_mfma_f32_16x16x32_bf16(afr[mt][0], bfr[nt][0], a, 0, 0, 0);
            a = __builtin_amdgcn_mfma_f32_16x16x32_bf16(afr[mt][1], bfr[nt][1], a, 0, 0, 0);
            acc1[mt][nt] = a;
        }

    // ---- epilogue: BN+SiLU, packed b64 writes into z[k][px] ----
    // D layout: k = nt*16+l15 (col), px0 = (wv*4+mt)*16 + l4*4 (4 consecutive px)
#pragma unroll
    for (int nt = 0; nt < 4; ++nt) {
        const int k = nt * 16 + l15;
        if (k < KK) {
            const float sc = sscale[k];
            const float bi = sbias[k];
#pragma unroll
            for (int mt = 0; mt < 4; ++mt) {
                const int px0 = (wv * 4 + mt) * 16 + l4 * 4;
                float v0, v1, v2, v3;
                {
                    const float t0 = acc1[mt][nt][0] * sc + bi;
                    const float t1 = acc1[mt][nt][1] * sc + bi;
                    const float t2 = acc1[mt][nt][2] * sc + bi;
                    const float t3 = acc1[mt][nt][3] * sc + bi;
                    v0 = __fdividef(t0, 1.0f + __expf(-t0));
                    v1 = __fdividef(t1, 1.0f + __expf(-t1));
                    v2 = __fdividef(t2, 1.0f + __expf(-t2));
                    v3 = __fdividef(t3, 1.0f + __expf(-t3));
                }
                u32x2 wpk;
                wpk[0] = f2bf(v0) | (f2bf(v1) << 16);
                wpk[1] = f2bf(v2) | (f2bf(v3) << 16);
                *(u32x2*)((char*)z_sh + k * ZROWB + px0 * 2) = wpk;
            }
        }
    }

    __syncthreads();   // z visible

    // ---- involution (dual): thread = (c2, y), computes 16 x outputs ----
    const int c2 = tid >> 4;
    const int y  = tid & 15;

    float a00 = 0.f, a01 = 0.f, a02 = 0.f, a03 = 0.f;
    float a04 = 0.f, a05 = 0.f, a06 = 0.f, a07 = 0.f;
    float a08 = 0.f, a09 = 0.f, a10 = 0.f, a11 = 0.f;
    float a12 = 0.f, a13 = 0.f, a14 = 0.f, a15 = 0.f;

    const float* hc = &halo[c2 * CSTRIDE];
    const char* zby = (const char*)z_sh + y * 32;   // + k*ZROWB

#pragma unroll
    for (int kh = 0; kh < KS; ++kh) {
        const float* hr = hc + (y + kh) * HALO_W;
        float row[22];
#pragma unroll
        for (int j = 0; j < 22; ++j) row[j] = hr[j];

#pragma unroll
        for (int kw = 0; kw < KS; ++kw) {
            const int k = kh * KS + kw;
            const char* zp = zby + k * ZROWB;
            const u32x4 q01 = *(const u32x4*)(zp);        // px x=0..7
            const u32x4 q23 = *(const u32x4*)(zp + 16);   // px x=8..15
            a00 = fmaf(BFLO(q01[0]), row[kw + 0],  a00);
            a01 = fmaf(BFHI(q01[0]), row[kw + 1],  a01);
            a02 = fmaf(BFLO(q01[1]), row[kw + 2],  a02);
            a03 = fmaf(BFHI(q01[1]), row[kw + 3],  a03);
            a04 = fmaf(BFLO(q01[2]), row[kw + 4],  a04);
            a05 = fmaf(BFHI(q01[2]), row[kw + 5],  a05);
            a06 = fmaf(BFLO(q01[3]), row[kw + 6],  a06);
            a07 = fmaf(BFHI(q01[3]), row[kw + 7],  a07);
            a08 = fmaf(BFLO(q23[0]), row[kw + 8],  a08);
            a09 = fmaf(BFHI(q23[0]), row[kw + 9],  a09);
            a10 = fmaf(BFLO(q23[1]), row[kw + 10], a10);
            a11 = fmaf(BFHI(q23[1]), row[kw + 11], a11);
            a12 = fmaf(BFLO(q23[2]), row[kw + 12], a12);
            a13 = fmaf(BFHI(q23[2]), row[kw + 13], a13);
            a14 = fmaf(BFLO(q23[3]), row[kw + 14], a14);
            a15 = fmaf(BFHI(q23[3]), row[kw + 15], a15);
        }
    }

    // ---- coalesced 16B stores ----
    float* og = out + (size_t)(b * C_ + g * GC_ + c2) * HW_ + (h0 + y) * W_ + w0;
    {
        f32x4 v;
        v[0] = a00; v[1] = a01; v[2] = a02; v[3] = a03;
        *(f32x4*)(og + 0) = v;
        v[0] = a04; v[1] = a05; v[2] = a06; v[3] = a07;
        *(f32x4*)(og + 4) = v;
        v[0] = a08; v[1] = a09; v[2] = a10; v[3] = a11;
        *(f32x4*)(og + 8) = v;
        v[0] = a12; v[1] = a13; v[2] = a14; v[3] = a15;
        *(f32x4*)(og + 12) = v;
    }
}

extern "C" void kernel_launch(void* const* d_in, const int* in_sizes, int n_in,
                              void* d_out, int out_size, void* d_ws, size_t ws_size,
                              hipStream_t stream) {
    const float* x   = (const float*)d_in[0];
    const float* cw  = (const float*)d_in[1];
    const float* bng = (const float*)d_in[2];
    const float* bnb = (const float*)d_in[3];
    const float* bnm = (const float*)d_in[4];
    const float* bnv = (const float*)d_in[5];
    float* out = (float*)d_out;

    dim3 grid(W_ / TW, H_ / TH, B_ * G_);   // 8 x 8 x 16
    dim3 block(256);
    invol_mfma3<<<grid, block, 0, stream>>>(x, cw, bng, bnb, bnm, bnv, out);
}

// Round 5
// 62.934 us; speedup vs baseline: 8.8308x; 8.8308x over previous
//
#include <hip/hip_runtime.h>

#define B_   4
#define C_   64
#define H_   128
#define W_   128
#define KS   7
#define G_   4
#define GC_  16
#define KK   49
#define PAD  3
#define TH   16
#define TW   16
#define HW_  (H_ * W_)
#define HALO_H 22
#define HALO_W 22
#define CSTRIDE 485            // dwords per halo channel (22*22+1, breaks bank pattern)
#define ZROWB 544              // bytes per z k-row: 256 px * 2B + 32B pad (16B aligned)

typedef float f32x4  __attribute__((ext_vector_type(4)));
typedef short bf16x8 __attribute__((ext_vector_type(8)));
typedef unsigned int u32x4 __attribute__((ext_vector_type(4)));
typedef unsigned int u32x2 __attribute__((ext_vector_type(2)));

__device__ __forceinline__ unsigned f2bf(float f) {   // RNE float->bf16 (low 16)
    unsigned u = __float_as_uint(f);
    unsigned r = u + 0x7FFFu + ((u >> 16) & 1u);
    return r >> 16;
}

#define BFLO(u) __uint_as_float((u) << 16)
#define BFHI(u) __uint_as_float((u) & 0xFFFF0000u)

__global__ __launch_bounds__(256, 2) void invol_mfma4(
    const float* __restrict__ x,
    const float* __restrict__ cw,
    const float* __restrict__ bng,
    const float* __restrict__ bnb,
    const float* __restrict__ bnm,
    const float* __restrict__ bnv,
    float* __restrict__ out)
{
    __shared__ float halo[GC_ * CSTRIDE];                        // 31040 B
    __shared__ __align__(16) unsigned short z_sh[KK * (ZROWB / 2)]; // 26656 B
    __shared__ float sscale[KK], sbias[KK];

    const int tid  = threadIdx.x;
    const int lane = tid & 63;
    const int wv   = tid >> 6;        // wave 0..3
    const int l15  = lane & 15;
    const int l4   = lane >> 4;

    const int w0 = blockIdx.x * TW;
    const int h0 = blockIdx.y * TH;
    const int bz = blockIdx.z;        // b*G + g
    const int b  = bz >> 2;
    const int g  = bz & 3;

    // ---- BN constants ----
    if (tid < KK) {
        const int o = g * KK + tid;
        const float s = bng[o] * rsqrtf(bnv[o] + 1e-5f);
        sscale[tid] = s;
        sbias[tid]  = bnb[o] - bnm[o] * s;
    }

    // ---- stage halo: [c][22r][22c], channel stride 485 dwords, zero-padded ----
    const float* xg = x + (size_t)(b * C_ + g * GC_) * HW_;
    for (int i = tid; i < GC_ * HALO_H * HALO_W; i += 256) {
        const int c  = i / (HALO_H * HALO_W);
        const int r  = i - c * (HALO_H * HALO_W);
        const int hh = r / HALO_W;
        const int ww = r - hh * HALO_W;
        const int gh = h0 + hh - PAD;
        const int gw = w0 + ww - PAD;
        float v = 0.0f;
        if (gh >= 0 && gh < H_ && gw >= 0 && gw < W_)
            v = xg[c * HW_ + gh * W_ + gw];
        halo[c * CSTRIDE + hh * HALO_W + ww] = v;
    }

    // ---- A fragments: A[px][c], px = (wv*4+mt)*16 + l15 ----
    bf16x8 afr[4][2];
    {
        const float* xb = x + (size_t)b * C_ * HW_;
#pragma unroll
        for (int mt = 0; mt < 4; ++mt) {
            const int hh = h0 + wv * 4 + mt;
            const float* xp = xb + hh * W_ + (w0 + l15);
#pragma unroll
            for (int ks = 0; ks < 2; ++ks) {
                const int c0 = ks * 32 + l4 * 8;
                bf16x8 a;
#pragma unroll
                for (int j = 0; j < 8; ++j)
                    a[j] = (short)f2bf(xp[(size_t)(c0 + j) * HW_]);
                afr[mt][ks] = a;
            }
        }
    }

    // ---- B fragments: B[c][k], k = nt*16 + l15 (zero-padded past 49) ----
    bf16x8 bfr[4][2];
    {
#pragma unroll
        for (int nt = 0; nt < 4; ++nt) {
            const int kout = nt * 16 + l15;
            const bool kv = (kout < KK);
            const float* wp = cw + (size_t)(g * KK + (kv ? kout : 0)) * C_;
#pragma unroll
            for (int ks = 0; ks < 2; ++ks) {
                const int c0 = ks * 32 + l4 * 8;
                bf16x8 bb;
#pragma unroll
                for (int j = 0; j < 8; ++j)
                    bb[j] = kv ? (short)f2bf(wp[c0 + j]) : (short)0;
                bfr[nt][ks] = bb;
            }
        }
    }

    __syncthreads();   // halo + BN consts staged

    // ---- MFMA: z[px][k] ----
    f32x4 acc1[4][4];
#pragma unroll
    for (int mt = 0; mt < 4; ++mt)
#pragma unroll
        for (int nt = 0; nt < 4; ++nt) {
            f32x4 a = {0.f, 0.f, 0.f, 0.f};
            a = __builtin_amdgcn_mfma_f32_16x16x32_bf16(afr[mt][0], bfr[nt][0], a, 0, 0, 0);
            a = __builtin_amdgcn_mfma_f32_16x16x32_bf16(afr[mt][1], bfr[nt][1], a, 0, 0, 0);
            acc1[mt][nt] = a;
        }

    // ---- epilogue: BN+SiLU, packed b64 writes into z[k][px] ----
    // D layout: k = nt*16+l15 (col), px0 = (wv*4+mt)*16 + l4*4 (4 consecutive px)
#pragma unroll
    for (int nt = 0; nt < 4; ++nt) {
        const int k = nt * 16 + l15;
        if (k < KK) {
            const float sc = sscale[k];
            const float bi = sbias[k];
#pragma unroll
            for (int mt = 0; mt < 4; ++mt) {
                const int px0 = (wv * 4 + mt) * 16 + l4 * 4;
                float v0, v1, v2, v3;
                {
                    const float t0 = acc1[mt][nt][0] * sc + bi;
                    const float t1 = acc1[mt][nt][1] * sc + bi;
                    const float t2 = acc1[mt][nt][2] * sc + bi;
                    const float t3 = acc1[mt][nt][3] * sc + bi;
                    v0 = __fdividef(t0, 1.0f + __expf(-t0));
                    v1 = __fdividef(t1, 1.0f + __expf(-t1));
                    v2 = __fdividef(t2, 1.0f + __expf(-t2));
                    v3 = __fdividef(t3, 1.0f + __expf(-t3));
                }
                u32x2 wpk;
                wpk[0] = f2bf(v0) | (f2bf(v1) << 16);
                wpk[1] = f2bf(v2) | (f2bf(v3) << 16);
                *(u32x2*)((char*)z_sh + k * ZROWB + px0 * 2) = wpk;
            }
        }
    }

    __syncthreads();   // z visible

    // ---- involution (dual): thread = (c2, y), computes 16 x outputs ----
    // kh loop deliberately NOT unrolled: keeps live-range peak ~160 VGPR
    // (full unroll made the scheduler hoist ~100 LDS loads -> acc spill,
    //  817 MB scratch writes in rounds 3-4). kw stays unrolled so row[]
    // indices are compile-time (rule #20).
    const int c2 = tid >> 4;
    const int y  = tid & 15;

    float a00 = 0.f, a01 = 0.f, a02 = 0.f, a03 = 0.f;
    float a04 = 0.f, a05 = 0.f, a06 = 0.f, a07 = 0.f;
    float a08 = 0.f, a09 = 0.f, a10 = 0.f, a11 = 0.f;
    float a12 = 0.f, a13 = 0.f, a14 = 0.f, a15 = 0.f;

    const float* hc = &halo[c2 * CSTRIDE];
    const char* zby = (const char*)z_sh + y * 32;   // + k*ZROWB

#pragma unroll 1
    for (int kh = 0; kh < KS; ++kh) {
        const float* hr = hc + (y + kh) * HALO_W;
        float row[22];
#pragma unroll
        for (int j = 0; j < 22; ++j) row[j] = hr[j];

        const char* zrow = zby + kh * (KS * ZROWB);
#pragma unroll
        for (int kw = 0; kw < KS; ++kw) {
            const char* zp = zrow + kw * ZROWB;
            const u32x4 q01 = *(const u32x4*)(zp);        // px x=0..7
            const u32x4 q23 = *(const u32x4*)(zp + 16);   // px x=8..15
            a00 = fmaf(BFLO(q01[0]), row[kw + 0],  a00);
            a01 = fmaf(BFHI(q01[0]), row[kw + 1],  a01);
            a02 = fmaf(BFLO(q01[1]), row[kw + 2],  a02);
            a03 = fmaf(BFHI(q01[1]), row[kw + 3],  a03);
            a04 = fmaf(BFLO(q01[2]), row[kw + 4],  a04);
            a05 = fmaf(BFHI(q01[2]), row[kw + 5],  a05);
            a06 = fmaf(BFLO(q01[3]), row[kw + 6],  a06);
            a07 = fmaf(BFHI(q01[3]), row[kw + 7],  a07);
            a08 = fmaf(BFLO(q23[0]), row[kw + 8],  a08);
            a09 = fmaf(BFHI(q23[0]), row[kw + 9],  a09);
            a10 = fmaf(BFLO(q23[1]), row[kw + 10], a10);
            a11 = fmaf(BFHI(q23[1]), row[kw + 11], a11);
            a12 = fmaf(BFLO(q23[2]), row[kw + 12], a12);
            a13 = fmaf(BFHI(q23[2]), row[kw + 13], a13);
            a14 = fmaf(BFLO(q23[3]), row[kw + 14], a14);
            a15 = fmaf(BFHI(q23[3]), row[kw + 15], a15);
        }
    }

    // ---- coalesced 16B stores ----
    float* og = out + (size_t)(b * C_ + g * GC_ + c2) * HW_ + (h0 + y) * W_ + w0;
    {
        f32x4 v;
        v[0] = a00; v[1] = a01; v[2] = a02; v[3] = a03;
        *(f32x4*)(og + 0) = v;
        v[0] = a04; v[1] = a05; v[2] = a06; v[3] = a07;
        *(f32x4*)(og + 4) = v;
        v[0] = a08; v[1] = a09; v[2] = a10; v[3] = a11;
        *(f32x4*)(og + 8) = v;
        v[0] = a12; v[1] = a13; v[2] = a14; v[3] = a15;
        *(f32x4*)(og + 12) = v;
    }
}

extern "C" void kernel_launch(void* const* d_in, const int* in_sizes, int n_in,
                              void* d_out, int out_size, void* d_ws, size_t ws_size,
                              hipStream_t stream) {
    const float* x   = (const float*)d_in[0];
    const float* cw  = (const float*)d_in[1];
    const float* bng = (const float*)d_in[2];
    const float* bnb = (const float*)d_in[3];
    const float* bnm = (const float*)d_in[4];
    const float* bnv = (const float*)d_in[5];
    float* out = (float*)d_out;

    dim3 grid(W_ / TW, H_ / TH, B_ * G_);   // 8 x 8 x 16
    dim3 block(256);
    invol_mfma4<<<grid, block, 0, stream>>>(x, cw, bng, bnb, bnm, bnv, out);
}

// Round 6
// 59.084 us; speedup vs baseline: 9.4062x; 1.0652x over previous
//
#include <hip/hip_runtime.h>

#define B_   4
#define C_   64
#define H_   128
#define W_   128
#define KS   7
#define G_   4
#define GC_  16
#define KK   49
#define PAD  3
#define TH   16
#define TW   16
#define HW_  (H_ * W_)
#define ZROWB 544              // bytes per z k-row: 256 px * 2B + 32B pad (16B aligned)

typedef float f32x4  __attribute__((ext_vector_type(4)));
typedef short bf16x8 __attribute__((ext_vector_type(8)));
typedef unsigned int u32x4 __attribute__((ext_vector_type(4)));
typedef unsigned int u32x2 __attribute__((ext_vector_type(2)));

__device__ __forceinline__ unsigned f2bf(float f) {   // RNE float->bf16 (low 16)
    unsigned u = __float_as_uint(f);
    unsigned r = u + 0x7FFFu + ((u >> 16) & 1u);
    return r >> 16;
}

#define BFLO(u) __uint_as_float((u) << 16)
#define BFHI(u) __uint_as_float((u) & 0xFFFF0000u)

__global__ __launch_bounds__(256, 4) void invol_mfma5(
    const float* __restrict__ x,
    const float* __restrict__ cw,
    const float* __restrict__ bng,
    const float* __restrict__ bnb,
    const float* __restrict__ bnm,
    const float* __restrict__ bnv,
    float* __restrict__ out)
{
    // LDS = z only: 26.7 KB -> 6-block capacity; grid caps residency at 4/CU
    __shared__ __align__(16) unsigned short z_sh[KK * (ZROWB / 2)]; // 26656 B
    __shared__ float sscale[KK], sbias[KK];

    const int tid  = threadIdx.x;
    const int lane = tid & 63;
    const int wv   = tid >> 6;        // wave 0..3
    const int l15  = lane & 15;
    const int l4   = lane >> 4;

    const int bx = blockIdx.x;
    const int w0 = bx * TW;
    const int h0 = blockIdx.y * TH;
    const int bz = blockIdx.z;        // b*G + g
    const int b  = bz >> 2;
    const int g  = bz & 3;

    // ---- BN constants ----
    if (tid < KK) {
        const int o = g * KK + tid;
        const float s = bng[o] * rsqrtf(bnv[o] + 1e-5f);
        sscale[tid] = s;
        sbias[tid]  = bnb[o] - bnm[o] * s;
    }

    // ---- A fragments: A[px][c], px = (wv*4+mt)*16 + l15 ----
    bf16x8 afr[4][2];
    {
        const float* xb = x + (size_t)b * C_ * HW_;
#pragma unroll
        for (int mt = 0; mt < 4; ++mt) {
            const int hh = h0 + wv * 4 + mt;
            const float* xp = xb + hh * W_ + (w0 + l15);
#pragma unroll
            for (int ks = 0; ks < 2; ++ks) {
                const int c0 = ks * 32 + l4 * 8;
                bf16x8 a;
#pragma unroll
                for (int j = 0; j < 8; ++j)
                    a[j] = (short)f2bf(xp[(size_t)(c0 + j) * HW_]);
                afr[mt][ks] = a;
            }
        }
    }

    // ---- B fragments: B[c][k], k = nt*16 + l15 (zero-padded past 49) ----
    bf16x8 bfr[4][2];
    {
#pragma unroll
        for (int nt = 0; nt < 4; ++nt) {
            const int kout = nt * 16 + l15;
            const bool kv = (kout < KK);
            const float* wp = cw + (size_t)(g * KK + (kv ? kout : 0)) * C_;
#pragma unroll
            for (int ks = 0; ks < 2; ++ks) {
                const int c0 = ks * 32 + l4 * 8;
                bf16x8 bb;
#pragma unroll
                for (int j = 0; j < 8; ++j)
                    bb[j] = kv ? (short)f2bf(wp[c0 + j]) : (short)0;
                bfr[nt][ks] = bb;
            }
        }
    }

    __syncthreads();   // sscale/sbias visible

    // ---- MFMA: z[px][k] ----
    f32x4 acc1[4][4];
#pragma unroll
    for (int mt = 0; mt < 4; ++mt)
#pragma unroll
        for (int nt = 0; nt < 4; ++nt) {
            f32x4 a = {0.f, 0.f, 0.f, 0.f};
            a = __builtin_amdgcn_mfma_f32_16x16x32_bf16(afr[mt][0], bfr[nt][0], a, 0, 0, 0);
            a = __builtin_amdgcn_mfma_f32_16x16x32_bf16(afr[mt][1], bfr[nt][1], a, 0, 0, 0);
            acc1[mt][nt] = a;
        }

    // ---- epilogue: BN+SiLU, packed b64 writes into z[k][px] ----
#pragma unroll
    for (int nt = 0; nt < 4; ++nt) {
        const int k = nt * 16 + l15;
        if (k < KK) {
            const float sc = sscale[k];
            const float bi = sbias[k];
#pragma unroll
            for (int mt = 0; mt < 4; ++mt) {
                const int px0 = (wv * 4 + mt) * 16 + l4 * 4;
                const float t0 = acc1[mt][nt][0] * sc + bi;
                const float t1 = acc1[mt][nt][1] * sc + bi;
                const float t2 = acc1[mt][nt][2] * sc + bi;
                const float t3 = acc1[mt][nt][3] * sc + bi;
                const float v0 = __fdividef(t0, 1.0f + __expf(-t0));
                const float v1 = __fdividef(t1, 1.0f + __expf(-t1));
                const float v2 = __fdividef(t2, 1.0f + __expf(-t2));
                const float v3 = __fdividef(t3, 1.0f + __expf(-t3));
                u32x2 wpk;
                wpk[0] = f2bf(v0) | (f2bf(v1) << 16);
                wpk[1] = f2bf(v2) | (f2bf(v3) << 16);
                *(u32x2*)((char*)z_sh + k * ZROWB + px0 * 2) = wpk;
            }
        }
    }

    __syncthreads();   // z visible

    // ---- involution: thread = (c2, y); x patches read from global via L1/L2 ----
    // (per-block distinct x footprint ~34 KB, L2-resident; deleting the halo
    //  LDS buffer bought 2 -> 4 blocks/CU residency)
    const int c2 = tid >> 4;
    const int y  = tid & 15;
    const bool xint = (bx != 0) & (bx != (W_ / TW - 1));

    float a00 = 0.f, a01 = 0.f, a02 = 0.f, a03 = 0.f;
    float a04 = 0.f, a05 = 0.f, a06 = 0.f, a07 = 0.f;
    float a08 = 0.f, a09 = 0.f, a10 = 0.f, a11 = 0.f;
    float a12 = 0.f, a13 = 0.f, a14 = 0.f, a15 = 0.f;

    const float* xc = x + (size_t)(b * C_ + g * GC_ + c2) * HW_;
    const char* zby = (const char*)z_sh + y * 32;   // + k*ZROWB

    // kh deliberately NOT unrolled (round-4 lesson: full unroll -> acc spill)
#pragma unroll 1
    for (int kh = 0; kh < KS; ++kh) {
        const int gh = h0 + y + kh - PAD;
        const bool rowok = (gh >= 0) & (gh < H_);
        const int ghc = gh < 0 ? 0 : (gh > H_ - 1 ? H_ - 1 : gh);
        const float* rp = xc + (size_t)ghc * W_;

        float row[22];
        if (xint) {
            const f32x4* vp = (const f32x4*)(rp + w0 - 4);
            const f32x4 q0 = vp[0], q1 = vp[1], q2 = vp[2],
                        q3 = vp[3], q4 = vp[4], q5 = vp[5];
            row[0] = q0[1]; row[1] = q0[2]; row[2] = q0[3];
#pragma unroll
            for (int j = 0; j < 4; ++j) {
                row[3 + j]  = q1[j];
                row[7 + j]  = q2[j];
                row[11 + j] = q3[j];
                row[15 + j] = q4[j];
            }
            row[19] = q5[0]; row[20] = q5[1]; row[21] = q5[2];
        } else if (bx == 0) {
            const f32x4* vp = (const f32x4*)rp;      // w0 == 0
            const f32x4 q0 = vp[0], q1 = vp[1], q2 = vp[2],
                        q3 = vp[3], q4 = vp[4];
            row[0] = 0.f; row[1] = 0.f; row[2] = 0.f;
#pragma unroll
            for (int j = 0; j < 4; ++j) {
                row[3 + j]  = q0[j];
                row[7 + j]  = q1[j];
                row[11 + j] = q2[j];
                row[15 + j] = q3[j];
            }
            row[19] = q4[0]; row[20] = q4[1]; row[21] = q4[2];
        } else {                                      // bx == 7
            const f32x4* vp = (const f32x4*)(rp + w0 - 4);
            const f32x4 q0 = vp[0], q1 = vp[1], q2 = vp[2],
                        q3 = vp[3], q4 = vp[4];
            row[0] = q0[1]; row[1] = q0[2]; row[2] = q0[3];
#pragma unroll
            for (int j = 0; j < 4; ++j) {
                row[3 + j]  = q1[j];
                row[7 + j]  = q2[j];
                row[11 + j] = q3[j];
                row[15 + j] = q4[j];
            }
            row[19] = 0.f; row[20] = 0.f; row[21] = 0.f;
        }

        if (rowok) {   // exec-mask predication: OOB rows contribute nothing
            const char* zrow = zby + kh * (KS * ZROWB);
#pragma unroll
            for (int kw = 0; kw < KS; ++kw) {
                const char* zp = zrow + kw * ZROWB;
                const u32x4 q01 = *(const u32x4*)(zp);        // px x=0..7
                const u32x4 q23 = *(const u32x4*)(zp + 16);   // px x=8..15
                a00 = fmaf(BFLO(q01[0]), row[kw + 0],  a00);
                a01 = fmaf(BFHI(q01[0]), row[kw + 1],  a01);
                a02 = fmaf(BFLO(q01[1]), row[kw + 2],  a02);
                a03 = fmaf(BFHI(q01[1]), row[kw + 3],  a03);
                a04 = fmaf(BFLO(q01[2]), row[kw + 4],  a04);
                a05 = fmaf(BFHI(q01[2]), row[kw + 5],  a05);
                a06 = fmaf(BFLO(q01[3]), row[kw + 6],  a06);
                a07 = fmaf(BFHI(q01[3]), row[kw + 7],  a07);
                a08 = fmaf(BFLO(q23[0]), row[kw + 8],  a08);
                a09 = fmaf(BFHI(q23[0]), row[kw + 9],  a09);
                a10 = fmaf(BFLO(q23[1]), row[kw + 10], a10);
                a11 = fmaf(BFHI(q23[1]), row[kw + 11], a11);
                a12 = fmaf(BFLO(q23[2]), row[kw + 12], a12);
                a13 = fmaf(BFHI(q23[2]), row[kw + 13], a13);
                a14 = fmaf(BFLO(q23[3]), row[kw + 14], a14);
                a15 = fmaf(BFHI(q23[3]), row[kw + 15], a15);
            }
        }
    }

    // ---- coalesced 16B stores ----
    float* og = out + (size_t)(b * C_ + g * GC_ + c2) * HW_ + (h0 + y) * W_ + w0;
    {
        f32x4 v;
        v[0] = a00; v[1] = a01; v[2] = a02; v[3] = a03;
        *(f32x4*)(og + 0) = v;
        v[0] = a04; v[1] = a05; v[2] = a06; v[3] = a07;
        *(f32x4*)(og + 4) = v;
        v[0] = a08; v[1] = a09; v[2] = a10; v[3] = a11;
        *(f32x4*)(og + 8) = v;
        v[0] = a12; v[1] = a13; v[2] = a14; v[3] = a15;
        *(f32x4*)(og + 12) = v;
    }
}

extern "C" void kernel_launch(void* const* d_in, const int* in_sizes, int n_in,
                              void* d_out, int out_size, void* d_ws, size_t ws_size,
                              hipStream_t stream) {
    const float* x   = (const float*)d_in[0];
    const float* cw  = (const float*)d_in[1];
    const float* bng = (const float*)d_in[2];
    const float* bnb = (const float*)d_in[3];
    const float* bnm = (const float*)d_in[4];
    const float* bnv = (const float*)d_in[5];
    float* out = (float*)d_out;

    dim3 grid(W_ / TW, H_ / TH, B_ * G_);   // 8 x 8 x 16
    dim3 block(256);
    invol_mfma5<<<grid, block, 0, stream>>>(x, cw, bng, bnb, bnm, bnv, out);
}